// Round 1
// baseline (493.419 us; speedup 1.0000x reference)
//
#include <hip/hip_runtime.h>

#define CC 256
#define NN 1024
#define CN (CC*NN)

// ---------------- grouped q/k projections ----------------
// z<12: xq[z][g*64+o][n] = sum_i Wq[g][o][i] * x[4+z][g*64+i][n]
// z>=12: xk[z-12][...] with Wk and x[z-12]
__global__ __launch_bounds__(256) void proj_qk_kernel(
    const float* __restrict__ x, const float* __restrict__ Wq,
    const float* __restrict__ Wk, float* __restrict__ xq, float* __restrict__ xk) {
  int n = blockIdx.x * 256 + threadIdx.x;
  int c = blockIdx.y;            // 0..255
  int z = blockIdx.z;            // 0..15
  int g = c >> 6, o = c & 63;
  const float* W; const float* src; float* dst;
  if (z < 12) { W = Wq; src = x + (long)(4 + z) * CN; dst = xq + (long)z * CN; }
  else        { W = Wk; src = x + (long)(z - 12) * CN; dst = xk + (long)(z - 12) * CN; }
  const float* w = W + (g * 64 + o) * 64;
  const float* xs = src + (long)(g * 64) * NN + n;
  float acc = 0.f;
#pragma unroll 8
  for (int i = 0; i < 64; ++i) acc += w[i] * xs[(long)i * NN];
  dst[(long)c * NN + n] = acc;
}

// ---------------- generic tiled fp32 GEMM ----------------
// C[i][j] = alpha * sum_k a(k,i)*b(k,j)  (+bias[j]) (+residual[i][j]) (relu?)
// AK: A stored k-major (addr k*lda+i), else i-major (addr i*lda+k). Same for BK.
#define TILE 64
#define KCH 16
#define LDSS 68   // padded row stride (17*16B -> float4-aligned rows, conflict-free-ish)

template<bool AK, bool BK>
__global__ __launch_bounds__(256) void gemm_kernel(
    const float* __restrict__ A, const float* __restrict__ B, float* __restrict__ Co,
    int M, int Nc, int K, int lda, int ldb, int ldc,
    long sA, int amod, long sB, int bmod, long sC,
    float alpha, const float* __restrict__ bias,
    const float* __restrict__ residual, int relu)
{
  __shared__ float As[KCH * LDSS];
  __shared__ float Bs[KCH * LDSS];
  int z = blockIdx.z;
  A += (long)(z % amod) * sA;
  B += (long)(z % bmod) * sB;
  Co += (long)z * sC;
  if (residual) residual += (long)z * sC;
  int j0 = blockIdx.x * TILE;
  int i0 = blockIdx.y * TILE;
  int t = threadIdx.x;
  int tx = t & 15, ty = t >> 4;   // tx -> j (coalesced stores), ty -> i
  float acc[4][4] = {{0.f}};
  for (int k0 = 0; k0 < K; k0 += KCH) {
#pragma unroll
    for (int r = 0; r < 4; ++r) {
      int idx = t + r * 256;
      if (AK) { int ii = idx & 63, kk = idx >> 6; As[kk*LDSS+ii] = A[(long)(k0+kk)*lda + i0+ii]; }
      else    { int kk = idx & 15, ii = idx >> 4; As[kk*LDSS+ii] = A[(long)(i0+ii)*lda + k0+kk]; }
    }
#pragma unroll
    for (int r = 0; r < 4; ++r) {
      int idx = t + r * 256;
      if (BK) { int jj = idx & 63, kk = idx >> 6; Bs[kk*LDSS+jj] = B[(long)(k0+kk)*ldb + j0+jj]; }
      else    { int kk = idx & 15, jj = idx >> 4; Bs[kk*LDSS+jj] = B[(long)(j0+jj)*ldb + k0+kk]; }
    }
    __syncthreads();
#pragma unroll
    for (int kk = 0; kk < KCH; ++kk) {
      float4 a4 = *(const float4*)&As[kk*LDSS + ty*4];
      float4 b4 = *(const float4*)&Bs[kk*LDSS + tx*4];
      float av[4] = {a4.x, a4.y, a4.z, a4.w};
      float bw[4] = {b4.x, b4.y, b4.z, b4.w};
#pragma unroll
      for (int r = 0; r < 4; ++r)
#pragma unroll
        for (int s = 0; s < 4; ++s)
          acc[r][s] += av[r] * bw[s];
    }
    __syncthreads();
  }
  int i = i0 + ty * 4, j = j0 + tx * 4;
  float4 bj = bias ? *(const float4*)&bias[j] : make_float4(0.f,0.f,0.f,0.f);
#pragma unroll
  for (int r = 0; r < 4; ++r) {
    float4 res = residual ? *(const float4*)&residual[(long)(i+r)*ldc + j]
                          : make_float4(0.f,0.f,0.f,0.f);
    float4 o;
    o.x = acc[r][0] * alpha + bj.x + res.x;
    o.y = acc[r][1] * alpha + bj.y + res.y;
    o.z = acc[r][2] * alpha + bj.z + res.z;
    o.w = acc[r][3] * alpha + bj.w + res.w;
    if (relu) { o.x = fmaxf(o.x,0.f); o.y = fmaxf(o.y,0.f); o.z = fmaxf(o.z,0.f); o.w = fmaxf(o.w,0.f); }
    *(float4*)&Co[(long)(i+r)*ldc + j] = o;
  }
}

// ---------------- row softmax over 1024 ----------------
__global__ __launch_bounds__(256) void softmax_kernel(float* __restrict__ E) {
  __shared__ float red[4];
  float* p = E + (long)blockIdx.x * NN;
  int t = threadIdx.x;
  float4 v = ((const float4*)p)[t];
  float m = fmaxf(fmaxf(v.x, v.y), fmaxf(v.z, v.w));
#pragma unroll
  for (int mask = 32; mask; mask >>= 1) m = fmaxf(m, __shfl_xor(m, mask));
  if ((t & 63) == 0) red[t >> 6] = m;
  __syncthreads();
  m = fmaxf(fmaxf(red[0], red[1]), fmaxf(red[2], red[3]));
  __syncthreads();
  v.x = __expf(v.x - m); v.y = __expf(v.y - m);
  v.z = __expf(v.z - m); v.w = __expf(v.w - m);
  float s = v.x + v.y + v.z + v.w;
#pragma unroll
  for (int mask = 32; mask; mask >>= 1) s += __shfl_xor(s, mask);
  if ((t & 63) == 0) red[t >> 6] = s;
  __syncthreads();
  s = red[0] + red[1] + red[2] + red[3];
  float inv = 1.f / s;
  v.x *= inv; v.y *= inv; v.z *= inv; v.w *= inv;
  ((float4*)p)[t] = v;
}

// ---------------- mix (reshape-mean) + residual + LN1 ----------------
// out[i] = first[i] + (x_r[3i]+x_r[3i+1]+x_r[3i+2])/3, then LN over c, store h[(i*1024+n)][c]
__global__ __launch_bounds__(256) void mix_ln1_kernel(
    const float* __restrict__ x, const float* __restrict__ xr,
    const float* __restrict__ g, const float* __restrict__ bb,
    float* __restrict__ h) {
  __shared__ float r1[4], r2[4];
  int bn = blockIdx.x;            // i*1024 + n
  int i = bn >> 10, n = bn & 1023;
  int c = threadIdx.x;
  long off = (long)c * NN + n;
  float v = x[(long)i * CN + off]
          + (xr[(long)(3*i+0) * CN + off]
           + xr[(long)(3*i+1) * CN + off]
           + xr[(long)(3*i+2) * CN + off]) * (1.f / 3.f);
  float s = v, s2 = v * v;
#pragma unroll
  for (int m = 32; m; m >>= 1) { s += __shfl_xor(s, m); s2 += __shfl_xor(s2, m); }
  if ((c & 63) == 0) { r1[c >> 6] = s; r2[c >> 6] = s2; }
  __syncthreads();
  float mu = (r1[0] + r1[1] + r1[2] + r1[3]) * (1.f / 256.f);
  float var = (r2[0] + r2[1] + r2[2] + r2[3]) * (1.f / 256.f) - mu * mu;
  h[(long)bn * CC + c] = (v - mu) * rsqrtf(var + 1e-6f) * g[c] + bb[c];
}

// ---------------- LN2 + relu + transpose out ----------------
__global__ __launch_bounds__(256) void ln2_out_kernel(
    const float* __restrict__ h2, const float* __restrict__ g,
    const float* __restrict__ bb, float* __restrict__ out) {
  __shared__ float r1[4], r2[4];
  int bn = blockIdx.x;
  int i = bn >> 10, n = bn & 1023;
  int c = threadIdx.x;
  float v = h2[(long)bn * CC + c];
  float s = v, s2 = v * v;
#pragma unroll
  for (int m = 32; m; m >>= 1) { s += __shfl_xor(s, m); s2 += __shfl_xor(s2, m); }
  if ((c & 63) == 0) { r1[c >> 6] = s; r2[c >> 6] = s2; }
  __syncthreads();
  float mu = (r1[0] + r1[1] + r1[2] + r1[3]) * (1.f / 256.f);
  float var = (r2[0] + r2[1] + r2[2] + r2[3]) * (1.f / 256.f) - mu * mu;
  float r = (v - mu) * rsqrtf(var + 1e-6f) * g[c] + bb[c];
  out[(long)i * CN + (long)c * NN + n] = fmaxf(r, 0.f);
}

extern "C" void kernel_launch(void* const* d_in, const int* in_sizes, int n_in,
                              void* d_out, int out_size, void* d_ws, size_t ws_size,
                              hipStream_t stream) {
  const float* x   = (const float*)d_in[0];
  const float* Wq  = (const float*)d_in[1];
  const float* Wk  = (const float*)d_in[2];
  const float* Wv  = (const float*)d_in[3];
  const float* bv  = (const float*)d_in[4];
  const float* g1  = (const float*)d_in[5];
  const float* b1v = (const float*)d_in[6];
  const float* W1  = (const float*)d_in[7];
  const float* b1m = (const float*)d_in[8];
  const float* W2  = (const float*)d_in[9];
  const float* b2m = (const float*)d_in[10];
  const float* g2  = (const float*)d_in[11];
  const float* b2v = (const float*)d_in[12];
  float* out = (float*)d_out;
  float* ws = (float*)d_ws;

  // workspace layout (floats); E region reused for h/hid/h2, xq reused for xr
  float* xq  = ws;                    // 12*CN
  float* xk  = xq + 12L * CN;         // 4*CN
  float* xvt = xk + 4L * CN;          // 4*CN  ([b][n][c])
  float* E   = xvt + 4L * CN;         // 12*NN*NN  (energy -> attn)
  float* xr  = xq;                    // 12*CN (xq dead by then)
  float* h   = E;                     // 4*NN*CC
  float* hid = h + 4L * NN * CC;      // 4*NN*1024
  float* h2  = hid + 4L * NN * 1024;  // 4*NN*CC

  // 1. grouped q/k projections
  proj_qk_kernel<<<dim3(4, 256, 16), 256, 0, stream>>>(x, Wq, Wk, xq, xk);

  // 2. xv_t[b][n][o] = sum_c Wv[o][c]*x[b][c][n] + bv[o]   (A k-major, B j-major)
  gemm_kernel<true, false><<<dim3(256/64, 1024/64, 4), 256, 0, stream>>>(
      x, Wv, xvt, 1024, 256, 256, NN, 256, 256,
      (long)CN, 4, 0L, 1, (long)NN * CC,
      1.f, bv, nullptr, 0);

  // 3. energy[q][n][m] = sum_c xq[q][c][n]*xk[q%4][c][m]
  gemm_kernel<true, true><<<dim3(16, 16, 12), 256, 0, stream>>>(
      xq, xk, E, 1024, 1024, 256, 1024, 1024, 1024,
      (long)CN, 12, (long)CN, 4, (long)NN * NN,
      1.f, nullptr, nullptr, 0);

  // 4. softmax rows
  softmax_kernel<<<12 * 1024, 256, 0, stream>>>(E);

  // 5. x_r[q][c][m] = (1/16) * sum_n xv_t[q%4][n][c] * attn[q][n][m]
  gemm_kernel<true, true><<<dim3(16, 4, 12), 256, 0, stream>>>(
      xvt, E, xr, 256, 1024, 1024, 256, 1024, 1024,
      (long)(NN * CC), 4, (long)NN * NN, 12, (long)CN,
      1.f / 16.f, nullptr, nullptr, 0);

  // 6. mix + residual + LN1 -> h[t][c]
  mix_ln1_kernel<<<4096, 256, 0, stream>>>(x, xr, g1, b1v, h);

  // 7. hid = relu(h @ W1^T + b1)
  gemm_kernel<false, false><<<dim3(1024/64, 4096/64, 1), 256, 0, stream>>>(
      h, W1, hid, 4096, 1024, 256, 256, 256, 1024,
      0L, 1, 0L, 1, 0L,
      1.f, b1m, nullptr, 1);

  // 8. h2 = hid @ W2^T + b2 + h
  gemm_kernel<false, false><<<dim3(256/64, 4096/64, 1), 256, 0, stream>>>(
      hid, W2, h2, 4096, 256, 1024, 1024, 1024, 256,
      0L, 1, 0L, 1, 0L,
      1.f, b2m, h, 0);

  // 9. LN2 + relu + transpose into out[0..3]
  ln2_out_kernel<<<4096, 256, 0, stream>>>(h2, g2, b2v, out);

  // 10. out[4..15] = x[4..15]
  hipMemcpyAsync(out + 4L * CN, x + 4L * CN, 12L * CN * sizeof(float),
                 hipMemcpyDeviceToDevice, stream);
}

// Round 3
// 243.538 us; speedup vs baseline: 2.0261x; 2.0261x over previous
//
#include <hip/hip_runtime.h>

#define CC 256
#define NN 1024
#define CN (CC*NN)

typedef __attribute__((ext_vector_type(8))) short short8;
typedef __attribute__((ext_vector_type(8))) unsigned short u16x8;
typedef __attribute__((ext_vector_type(4))) float f32x4;

__device__ __forceinline__ unsigned short f2bf(float x) {
  unsigned u = __float_as_uint(x);
  u = u + 0x7fffu + ((u >> 16) & 1u);
  return (unsigned short)(u >> 16);
}
__device__ __forceinline__ float bf2f(unsigned short b) {
  return __uint_as_float(((unsigned)b) << 16);
}
__device__ __forceinline__ void gload_lds16(const unsigned short* g, unsigned short* l) {
  __builtin_amdgcn_global_load_lds(
      (const __attribute__((address_space(1))) unsigned short*)g,
      (__attribute__((address_space(3))) unsigned short*)l, 16, 0, 0);
}

// ---------- weight conversion f32 -> bf16 (Wv, W1, W2) ----------
// float4 counts: Wv 16384, W1 65536, W2 65536  -> total 147456 (576 blocks)
__global__ __launch_bounds__(256) void convert_w(
    const float4* __restrict__ Wv, const float4* __restrict__ W1,
    const float4* __restrict__ W2, unsigned short* __restrict__ wv_bf,
    unsigned short* __restrict__ w1_bf, unsigned short* __restrict__ w2_bf) {
  int id = blockIdx.x * 256 + threadIdx.x;
  const float4* s; unsigned short* d; int k;
  if (id < 16384)      { s = Wv; d = wv_bf; k = id; }
  else if (id < 81920) { s = W1; d = w1_bf; k = id - 16384; }
  else                 { s = W2; d = w2_bf; k = id - 81920; }
  float4 v = s[k];
  ushort4 o; o.x = f2bf(v.x); o.y = f2bf(v.y); o.z = f2bf(v.z); o.w = f2bf(v.w);
  *(ushort4*)&d[k * 4] = o;
}

// ---------- transpose first-4 batches: x[b][c][n] -> xT_bf[b][n][c] ----------
__global__ __launch_bounds__(256) void transpose_x(
    const float* __restrict__ x, unsigned short* __restrict__ xT) {
  __shared__ float tile[64][65];
  int b = blockIdx.z, c0 = blockIdx.y * 64, n0 = blockIdx.x * 64;
  int t = threadIdx.x, tr = t >> 6, tc = t & 63;
#pragma unroll
  for (int r = 0; r < 16; ++r) {
    int c = tr + r * 4;
    tile[c][tc] = x[(long)b * CN + (long)(c0 + c) * NN + n0 + tc];
  }
  __syncthreads();
#pragma unroll
  for (int r = 0; r < 16; ++r) {
    int n = tr + r * 4;
    xT[(long)b * CN + (long)(n0 + n) * CC + c0 + tc] = f2bf(tile[tc][n]);
  }
}

// ---------- grouped q/k projection, writes [n][c] bf16 ----------
__global__ __launch_bounds__(256) void proj_kernel(
    const float* __restrict__ x, const float* __restrict__ Wq,
    const float* __restrict__ Wk, unsigned short* __restrict__ xqT,
    unsigned short* __restrict__ xkT) {
  __shared__ float xs[64][68];
  __shared__ float Ws[64][65];
  int z = blockIdx.z, g = blockIdx.y, n0 = blockIdx.x * 64;
  const float* src; const float* W; unsigned short* dst;
  if (z < 12) { src = x + (long)(4 + z) * CN; W = Wq; dst = xqT + (long)z * CN; }
  else        { src = x + (long)(z - 12) * CN; W = Wk; dst = xkT + (long)(z - 12) * CN; }
  int t = threadIdx.x, tr = t >> 6, tc = t & 63;
#pragma unroll
  for (int r = 0; r < 16; ++r) {
    int i = tr + r * 4;
    xs[i][tc] = src[(long)(g * 64 + i) * NN + n0 + tc];
    Ws[i][tc] = W[(g * 64 + i) * 64 + tc];
  }
  __syncthreads();
  int o = tc, q = tr;
  float acc[16];
#pragma unroll
  for (int k = 0; k < 16; ++k) acc[k] = 0.f;
  for (int i = 0; i < 64; ++i) {
    float w = Ws[o][i];
    const float4* xr4 = (const float4*)&xs[i][q * 16];
#pragma unroll
    for (int k = 0; k < 4; ++k) {
      float4 v = xr4[k];
      acc[4*k+0] += w * v.x; acc[4*k+1] += w * v.y;
      acc[4*k+2] += w * v.z; acc[4*k+3] += w * v.w;
    }
  }
#pragma unroll
  for (int k = 0; k < 16; ++k)
    dst[(long)(n0 + q * 16 + k) * CC + g * 64 + o] = f2bf(acc[k]);
}

// ---------- bf16 MFMA GEMM, 128x128 tile ----------
// out[i][j] = alpha*sum_k A[i][k]*B[j][k] (+bias) (+res) (relu?)
template<int BIASROW, int BIASCOL, int RELU, int RES, int OUTBF>
__global__ __launch_bounds__(256) void mgemm(
    const unsigned short* __restrict__ A, const unsigned short* __restrict__ B,
    void* __restrict__ Cout, const float* __restrict__ bias,
    const float* __restrict__ res,
    int lda, int ldb, int ldc, int K,
    long sA, int amod, long sB, int bmod, long sC, long sR, float alpha) {
  __shared__ unsigned short As[128 * 32];
  __shared__ unsigned short Bs[128 * 32];
  int z = blockIdx.z;
  A += (long)(z % amod) * sA;
  B += (long)(z % bmod) * sB;
  int t = threadIdx.x, w = t >> 6, l = t & 63;
  int wr = w >> 1, wc = w & 1;
  long i0 = blockIdx.y * 128, j0 = blockIdx.x * 128;
  f32x4 acc[4][4];
#pragma unroll
  for (int a = 0; a < 4; ++a)
#pragma unroll
    for (int b = 0; b < 4; ++b) acc[a][b] = (f32x4){0.f, 0.f, 0.f, 0.f};
  int lr = l & 15, lk = (l >> 4) * 8;
  for (int k0 = 0; k0 < K; k0 += 32) {
#pragma unroll
    for (int it = 0; it < 2; ++it) {
      int chunk = t + it * 256;
      int row = chunk >> 2, kq = chunk & 3;
      gload_lds16(A + (i0 + row) * (long)lda + k0 + kq * 8, &As[chunk * 8]);
      gload_lds16(B + (j0 + row) * (long)ldb + k0 + kq * 8, &Bs[chunk * 8]);
    }
    __syncthreads();
    short8 af[4], bfr[4];
#pragma unroll
    for (int f = 0; f < 4; ++f) af[f]  = *(const short8*)&As[(wr * 64 + f * 16 + lr) * 32 + lk];
#pragma unroll
    for (int f = 0; f < 4; ++f) bfr[f] = *(const short8*)&Bs[(wc * 64 + f * 16 + lr) * 32 + lk];
#pragma unroll
    for (int fm = 0; fm < 4; ++fm)
#pragma unroll
      for (int fn = 0; fn < 4; ++fn)
        acc[fm][fn] = __builtin_amdgcn_mfma_f32_16x16x32_bf16(af[fm], bfr[fn], acc[fm][fn], 0, 0, 0);
    __syncthreads();
  }
  long cz = (long)z * sC;
  long rz = (long)z * sR;
  int li = (l >> 4) * 4, lj = l & 15;
#pragma unroll
  for (int fm = 0; fm < 4; ++fm)
#pragma unroll
    for (int fn = 0; fn < 4; ++fn) {
      long ib = i0 + wr * 64 + fm * 16 + li;
      long j  = j0 + wc * 64 + fn * 16 + lj;
#pragma unroll
      for (int r = 0; r < 4; ++r) {
        long i = ib + r;
        float v = acc[fm][fn][r] * alpha;
        if (BIASCOL) v += bias[j];
        if (BIASROW) v += bias[i];
        if (RES)     v += res[rz + i * ldc + j];
        if (RELU)    v = fmaxf(v, 0.f);
        if (OUTBF) ((unsigned short*)Cout)[cz + i * ldc + j] = f2bf(v);
        else       ((float*)Cout)[cz + i * ldc + j] = v;
      }
    }
}

// ---------- softmax stats over m (E'[q][m][n] bf16) ----------
__global__ __launch_bounds__(256) void smax_part(
    const unsigned short* __restrict__ E, float* __restrict__ part) {
  int n = blockIdx.x * 256 + threadIdx.x;
  int mc = blockIdx.y, q = blockIdx.z;
  const unsigned short* p = E + (long)q * NN * NN + (long)mc * 128 * NN + n;
  float mx = -1e30f;
#pragma unroll 8
  for (int m = 0; m < 128; ++m) mx = fmaxf(mx, bf2f(p[(long)m * NN]));
  float sm = 0.f;
#pragma unroll 8
  for (int m = 0; m < 128; ++m) sm += __expf(bf2f(p[(long)m * NN]) - mx);
  long o = ((long)q * 8 + mc) * NN + n;
  part[2 * o] = mx;
  part[2 * o + 1] = sm;
}

__global__ __launch_bounds__(256) void smax_comb(
    const float* __restrict__ part, float* __restrict__ stat) {
  int n = blockIdx.x * 256 + threadIdx.x;
  int q = blockIdx.y;
  float mx = -1e30f;
#pragma unroll
  for (int c = 0; c < 8; ++c) mx = fmaxf(mx, part[(((long)q * 8 + c) * NN + n) * 2]);
  float sm = 0.f;
#pragma unroll
  for (int c = 0; c < 8; ++c) {
    long o = (((long)q * 8 + c) * NN + n) * 2;
    sm += part[o + 1] * __expf(part[o] - mx);
  }
  stat[((long)q * NN + n) * 2] = mx;
  stat[((long)q * NN + n) * 2 + 1] = 1.f / sm;
}

// ---------- PV GEMM with fused exp: xrT[z][m][c] = (1/16) sum_n p(E[m][n]) * xv[c][n] ----------
__global__ __launch_bounds__(256) void pv_gemm(
    const unsigned short* __restrict__ E, const unsigned short* __restrict__ XV,
    const float* __restrict__ stat, float* __restrict__ xrT) {
  __shared__ unsigned short As[128 * 32];
  __shared__ unsigned short Bs[128 * 32];
  __shared__ float Ms[1024];
  __shared__ float Ds[1024];
  int z = blockIdx.z;
  const unsigned short* A = E + (long)z * NN * NN;
  const unsigned short* B = XV + (long)(z & 3) * CN;
  const float* st = stat + (long)z * NN * 2;
  int t = threadIdx.x;
#pragma unroll
  for (int i = 0; i < 4; ++i) {
    int n = i * 256 + t;
    float2 s2 = *(const float2*)&st[n * 2];
    Ms[n] = s2.x; Ds[n] = s2.y;
  }
  int w = t >> 6, l = t & 63;
  int wr = w >> 1, wc = w & 1;
  long i0 = blockIdx.y * 128, j0 = blockIdx.x * 128;
  f32x4 acc[4][4];
#pragma unroll
  for (int a = 0; a < 4; ++a)
#pragma unroll
    for (int b = 0; b < 4; ++b) acc[a][b] = (f32x4){0.f, 0.f, 0.f, 0.f};
  int lr = l & 15, lk = (l >> 4) * 8;
  int ar = t >> 1, ah = (t & 1) * 16;
  __syncthreads();
  for (int k0 = 0; k0 < 1024; k0 += 32) {
#pragma unroll
    for (int it = 0; it < 2; ++it) {
      int chunk = t + it * 256;
      int row = chunk >> 2, kq = chunk & 3;
      gload_lds16(B + (j0 + row) * 1024L + k0 + kq * 8, &Bs[chunk * 8]);
    }
    u16x8 e0 = *(const u16x8*)&A[(i0 + ar) * 1024L + k0 + ah];
    u16x8 e1 = *(const u16x8*)&A[(i0 + ar) * 1024L + k0 + ah + 8];
    u16x8 p0, p1;
#pragma unroll
    for (int j = 0; j < 8; ++j) {
      int n = k0 + ah + j;
      p0[j] = f2bf(__expf(bf2f(e0[j]) - Ms[n]) * Ds[n]);
    }
#pragma unroll
    for (int j = 0; j < 8; ++j) {
      int n = k0 + ah + 8 + j;
      p1[j] = f2bf(__expf(bf2f(e1[j]) - Ms[n]) * Ds[n]);
    }
    *(u16x8*)&As[ar * 32 + ah]     = p0;
    *(u16x8*)&As[ar * 32 + ah + 8] = p1;
    __syncthreads();
    short8 af[4], bfr[4];
#pragma unroll
    for (int f = 0; f < 4; ++f) af[f]  = *(const short8*)&As[(wr * 64 + f * 16 + lr) * 32 + lk];
#pragma unroll
    for (int f = 0; f < 4; ++f) bfr[f] = *(const short8*)&Bs[(wc * 64 + f * 16 + lr) * 32 + lk];
#pragma unroll
    for (int fm = 0; fm < 4; ++fm)
#pragma unroll
      for (int fn = 0; fn < 4; ++fn)
        acc[fm][fn] = __builtin_amdgcn_mfma_f32_16x16x32_bf16(af[fm], bfr[fn], acc[fm][fn], 0, 0, 0);
    __syncthreads();
  }
  long cz = (long)z * CN;
  int li = (l >> 4) * 4, lj = l & 15;
#pragma unroll
  for (int fm = 0; fm < 4; ++fm)
#pragma unroll
    for (int fn = 0; fn < 4; ++fn) {
      long ib = i0 + wr * 64 + fm * 16 + li;
      long j  = j0 + wc * 64 + fn * 16 + lj;
#pragma unroll
      for (int r = 0; r < 4; ++r)
        xrT[cz + (ib + r) * 256 + j] = acc[fm][fn][r] * (1.f / 16.f);
    }
}

// ---------- mix (reshape-mean) + residual + LN1 ----------
__global__ __launch_bounds__(256) void mix_ln1(
    const unsigned short* __restrict__ xT, const float* __restrict__ xrT,
    const float* __restrict__ g, const float* __restrict__ bb,
    float* __restrict__ h, unsigned short* __restrict__ h_bf) {
  __shared__ float r1[4], r2[4];
  int bn = blockIdx.x;
  int i = bn >> 10, n = bn & 1023;
  int c = threadIdx.x;
  long no = (long)n * CC + c;
  float v = bf2f(xT[(long)i * CN + no])
          + (xrT[(long)(3 * i + 0) * CN + no]
           + xrT[(long)(3 * i + 1) * CN + no]
           + xrT[(long)(3 * i + 2) * CN + no]) * (1.f / 3.f);
  float s = v, s2 = v * v;
#pragma unroll
  for (int m = 32; m; m >>= 1) { s += __shfl_xor(s, m); s2 += __shfl_xor(s2, m); }
  if ((c & 63) == 0) { r1[c >> 6] = s; r2[c >> 6] = s2; }
  __syncthreads();
  float mu = (r1[0] + r1[1] + r1[2] + r1[3]) * (1.f / 256.f);
  float var = (r2[0] + r2[1] + r2[2] + r2[3]) * (1.f / 256.f) - mu * mu;
  float o = (v - mu) * rsqrtf(var + 1e-6f) * g[c] + bb[c];
  h[(long)bn * CC + c] = o;
  h_bf[(long)bn * CC + c] = f2bf(o);
}

// ---------- LN2 + relu + transpose to out[i][c][n] ----------
__global__ __launch_bounds__(256) void ln2t(
    const float* __restrict__ h2, const float* __restrict__ g,
    const float* __restrict__ bb, float* __restrict__ out) {
  __shared__ float tile[16][261];
  __shared__ float smu[16], srs[16];
  int i = blockIdx.y, n0 = blockIdx.x * 16;
  int t = threadIdx.x;
#pragma unroll
  for (int r = 0; r < 16; ++r)
    tile[r][t] = h2[((long)i * NN + n0 + r) * CC + t];
  __syncthreads();
  int w = t >> 6, l = t & 63;
#pragma unroll
  for (int rr = 0; rr < 4; ++rr) {
    int r = w * 4 + rr;
    float s = 0.f, s2 = 0.f;
#pragma unroll
    for (int k = 0; k < 4; ++k) { float v = tile[r][l + 64 * k]; s += v; s2 += v * v; }
#pragma unroll
    for (int m = 32; m; m >>= 1) { s += __shfl_xor(s, m); s2 += __shfl_xor(s2, m); }
    if (l == 0) {
      float mu = s * (1.f / 256.f);
      float var = s2 * (1.f / 256.f) - mu * mu;
      smu[r] = mu; srs[r] = rsqrtf(var + 1e-6f);
    }
  }
  __syncthreads();
#pragma unroll
  for (int k = 0; k < 16; ++k) {
    int nn = t & 15, c = (t >> 4) + 16 * k;
    float v = (tile[nn][c] - smu[nn]) * srs[nn] * g[c] + bb[c];
    out[((long)i * CC + c) * NN + n0 + nn] = fmaxf(v, 0.f);
  }
}

extern "C" void kernel_launch(void* const* d_in, const int* in_sizes, int n_in,
                              void* d_out, int out_size, void* d_ws, size_t ws_size,
                              hipStream_t stream) {
  const float* x   = (const float*)d_in[0];
  const float* Wq  = (const float*)d_in[1];
  const float* Wk  = (const float*)d_in[2];
  const float* Wv  = (const float*)d_in[3];
  const float* bv  = (const float*)d_in[4];
  const float* g1  = (const float*)d_in[5];
  const float* b1v = (const float*)d_in[6];
  const float* W1  = (const float*)d_in[7];
  const float* b1m = (const float*)d_in[8];
  const float* W2  = (const float*)d_in[9];
  const float* b2m = (const float*)d_in[10];
  const float* g2  = (const float*)d_in[11];
  const float* b2v = (const float*)d_in[12];
  float* out = (float*)d_out;

  char* base = (char*)d_ws;
  // E region 24MB; after PV it is reused for h / h_bf / hid_bf / h2
  unsigned short* E_bf   = (unsigned short*)base;
  float*          h      = (float*)base;                           // [0,4MB)
  unsigned short* h_bf   = (unsigned short*)(base + (4u << 20));   // [4,6)
  unsigned short* hid_bf = (unsigned short*)(base + (6u << 20));   // [6,14)
  float*          h2     = (float*)(base + (14u << 20));           // [14,18)
  size_t off = 24u << 20;
  float* xrT             = (float*)(base + off);          off += 12582912;
  unsigned short* wv_bf  = (unsigned short*)(base + off); off += 131072;
  unsigned short* w1_bf  = (unsigned short*)(base + off); off += 524288;
  unsigned short* w2_bf  = (unsigned short*)(base + off); off += 524288;
  unsigned short* xt_bf  = (unsigned short*)(base + off); off += 2097152;
  unsigned short* xqt_bf = (unsigned short*)(base + off); off += 6291456;
  unsigned short* xkt_bf = (unsigned short*)(base + off); off += 2097152;
  unsigned short* xv_bf  = (unsigned short*)(base + off); off += 2097152;
  float* part            = (float*)(base + off); off += 786432;
  float* stat            = (float*)(base + off); off += 98304;

  // 1. weights -> bf16 (147456 float4s, 576 blocks)
  convert_w<<<576, 256, 0, stream>>>((const float4*)Wv, (const float4*)W1,
                                     (const float4*)W2, wv_bf, w1_bf, w2_bf);
  // 2. xT_bf[b][n][c] for b<4
  transpose_x<<<dim3(16, 4, 4), 256, 0, stream>>>(x, xt_bf);
  // 3. projections -> xqT[12], xkT[4]  ([n][c] bf16)
  proj_kernel<<<dim3(16, 4, 16), 256, 0, stream>>>(x, Wq, Wk, xqt_bf, xkt_bf);
  // 4. xv_bf[b][o][n] = Wv x[b] + bv
  mgemm<1,0,0,0,1><<<dim3(8, 2, 4), 256, 0, stream>>>(
      wv_bf, xt_bf, xv_bf, bv, nullptr,
      256, 256, 1024, 256, 0L, 1, (long)CN, 4, (long)CN, 0L, 1.f);
  // 5. E'[z][m][n] = sum_c xk[c][m] xq[c][n]  (bf16)
  mgemm<0,0,0,0,1><<<dim3(8, 8, 12), 256, 0, stream>>>(
      xkt_bf, xqt_bf, E_bf, nullptr, nullptr,
      256, 256, 1024, 256, (long)CN, 4, (long)CN, 12, (long)NN * NN, 0L, 1.f);
  // 6-7. softmax stats over m
  smax_part<<<dim3(4, 8, 12), 256, 0, stream>>>(E_bf, part);
  smax_comb<<<dim3(4, 12), 256, 0, stream>>>(part, stat);
  // 8. PV with fused exp -> xrT[z][m][c] f32
  pv_gemm<<<dim3(2, 8, 12), 256, 0, stream>>>(E_bf, xv_bf, stat, xrT);
  // 9. mix + LN1 -> h (f32) + h_bf
  mix_ln1<<<4096, 256, 0, stream>>>(xt_bf, xrT, g1, b1v, h, h_bf);
  // 10. hid = relu(h @ W1^T + b1) -> bf16
  mgemm<0,1,1,0,1><<<dim3(8, 32, 1), 256, 0, stream>>>(
      h_bf, w1_bf, hid_bf, b1m, nullptr,
      256, 256, 1024, 256, 0L, 1, 0L, 1, 0L, 0L, 1.f);
  // 11. h2 = hid @ W2^T + b2 + h -> f32
  mgemm<0,1,0,1,0><<<dim3(2, 32, 1), 256, 0, stream>>>(
      hid_bf, w2_bf, h2, b2m, h,
      1024, 1024, 256, 1024, 0L, 1, 0L, 1, 0L, 0L, 1.f);
  // 12. LN2 + relu + transpose -> out[0..3]
  ln2t<<<dim3(64, 4), 256, 0, stream>>>(h2, g2, b2v, out);
  // 13. passthrough batches 4..15
  hipMemcpyAsync(out + 4L * CN, x + 4L * CN, 12L * CN * sizeof(float),
                 hipMemcpyDeviceToDevice, stream);
}

// Round 4
// 195.864 us; speedup vs baseline: 2.5192x; 1.2434x over previous
//
#include <hip/hip_runtime.h>

#define CC 256
#define NN 1024
#define CN (CC*NN)

typedef __attribute__((ext_vector_type(8))) short short8;
typedef __attribute__((ext_vector_type(8))) unsigned short u16x8;
typedef __attribute__((ext_vector_type(4))) float f32x4;

__device__ __forceinline__ unsigned short f2bf(float x) {
  unsigned u = __float_as_uint(x);
  u = u + 0x7fffu + ((u >> 16) & 1u);
  return (unsigned short)(u >> 16);
}
__device__ __forceinline__ float bf2f(unsigned short b) {
  return __uint_as_float(((unsigned)b) << 16);
}
__device__ __forceinline__ void gload_lds16(const unsigned short* g, unsigned short* l) {
  __builtin_amdgcn_global_load_lds(
      (const __attribute__((address_space(1))) unsigned short*)g,
      (__attribute__((address_space(3))) unsigned short*)l, 16, 0, 0);
}

// ---------- prep: weight convert + x-transpose + q/k projections (one launch) ----------
__global__ __launch_bounds__(256) void prep_kernel(
    const float* __restrict__ x, const float* __restrict__ Wq,
    const float* __restrict__ Wk, const float4* __restrict__ Wv,
    const float4* __restrict__ W1, const float4* __restrict__ W2,
    unsigned short* __restrict__ wv_bf, unsigned short* __restrict__ w1_bf,
    unsigned short* __restrict__ w2_bf, unsigned short* __restrict__ xT,
    unsigned short* __restrict__ xqT, unsigned short* __restrict__ xkT) {
  __shared__ float shbuf[64 * 133];
  int bz = blockIdx.x, t = threadIdx.x;
  if (bz < 576) {
    // convert 147456 float4s: Wv 16384, W1 65536, W2 65536
    int id = bz * 256 + t;
    const float4* s; unsigned short* d; int k;
    if (id < 16384)      { s = Wv; d = wv_bf; k = id; }
    else if (id < 81920) { s = W1; d = w1_bf; k = id - 16384; }
    else                 { s = W2; d = w2_bf; k = id - 81920; }
    float4 v = s[k];
    ushort4 o; o.x = f2bf(v.x); o.y = f2bf(v.y); o.z = f2bf(v.z); o.w = f2bf(v.w);
    *(ushort4*)&d[k * 4] = o;
  } else if (bz < 832) {
    // transpose x[b][c][n] -> xT[b][n][c] bf16 (b<4)
    float (*tile)[65] = (float(*)[65])shbuf;
    int zz = bz - 576;
    int b = zz >> 6, c0 = ((zz >> 4) & 3) * 64, n0 = (zz & 15) * 64;
    int tr = t >> 6, tc = t & 63;
#pragma unroll
    for (int r = 0; r < 16; ++r) {
      int c = tr + r * 4;
      tile[c][tc] = x[(long)b * CN + (long)(c0 + c) * NN + n0 + tc];
    }
    __syncthreads();
#pragma unroll
    for (int r = 0; r < 16; ++r) {
      int n = tr + r * 4;
      xT[(long)b * CN + (long)(n0 + n) * CC + c0 + tc] = f2bf(tile[tc][n]);
    }
  } else {
    // grouped projections -> xqT[12], xkT[4]  ([n][c] bf16)
    float (*xs)[68] = (float(*)[68])shbuf;
    float (*Ws)[65] = (float(*)[65])(shbuf + 64 * 68);
    int zz = bz - 832;
    int z = zz >> 6, g = (zz >> 4) & 3, n0 = (zz & 15) * 64;
    const float* src; const float* W; unsigned short* dst;
    if (z < 12) { src = x + (long)(4 + z) * CN; W = Wq; dst = xqT + (long)z * CN; }
    else        { src = x + (long)(z - 12) * CN; W = Wk; dst = xkT + (long)(z - 12) * CN; }
    int tr = t >> 6, tc = t & 63;
#pragma unroll
    for (int r = 0; r < 16; ++r) {
      int i = tr + r * 4;
      xs[i][tc] = src[(long)(g * 64 + i) * NN + n0 + tc];
      Ws[i][tc] = W[(g * 64 + i) * 64 + tc];
    }
    __syncthreads();
    int o = tc, q = tr;
    float acc[16];
#pragma unroll
    for (int k = 0; k < 16; ++k) acc[k] = 0.f;
    for (int i = 0; i < 64; ++i) {
      float w = Ws[o][i];
      const float4* xr4 = (const float4*)&xs[i][q * 16];
#pragma unroll
      for (int k = 0; k < 4; ++k) {
        float4 v = xr4[k];
        acc[4*k+0] += w * v.x; acc[4*k+1] += w * v.y;
        acc[4*k+2] += w * v.z; acc[4*k+3] += w * v.w;
      }
    }
#pragma unroll
    for (int k = 0; k < 16; ++k)
      dst[(long)(n0 + q * 16 + k) * CC + g * 64 + o] = f2bf(acc[k]);
  }
}

// ---------- bf16 MFMA GEMM, 128x128 tile; optional fused column-softmax stats ----------
template<int BIASROW, int BIASCOL, int RELU, int RES, int OUTBF, int STATS>
__global__ __launch_bounds__(256) void mgemm(
    const unsigned short* __restrict__ A, const unsigned short* __restrict__ B,
    void* __restrict__ Cout, const float* __restrict__ bias,
    const float* __restrict__ res, float2* __restrict__ part,
    int lda, int ldb, int ldc, int K,
    long sA, int amod, long sB, int bmod, long sC, long sR, float alpha) {
  __shared__ unsigned short As[128 * 32];
  __shared__ unsigned short Bs[128 * 32];
  int z = blockIdx.z;
  A += (long)(z % amod) * sA;
  B += (long)(z % bmod) * sB;
  int t = threadIdx.x, w = t >> 6, l = t & 63;
  int wr = w >> 1, wc = w & 1;
  long i0 = blockIdx.y * 128, j0 = blockIdx.x * 128;
  f32x4 acc[4][4];
#pragma unroll
  for (int a = 0; a < 4; ++a)
#pragma unroll
    for (int b = 0; b < 4; ++b) acc[a][b] = (f32x4){0.f, 0.f, 0.f, 0.f};
  int lr = l & 15, lk = (l >> 4) * 8;
  for (int k0 = 0; k0 < K; k0 += 32) {
#pragma unroll
    for (int it = 0; it < 2; ++it) {
      int chunk = t + it * 256;
      int row = chunk >> 2, kq = chunk & 3;
      gload_lds16(A + (i0 + row) * (long)lda + k0 + kq * 8, &As[chunk * 8]);
      gload_lds16(B + (j0 + row) * (long)ldb + k0 + kq * 8, &Bs[chunk * 8]);
    }
    __syncthreads();
    short8 af[4], bfr[4];
#pragma unroll
    for (int f = 0; f < 4; ++f) af[f]  = *(const short8*)&As[(wr * 64 + f * 16 + lr) * 32 + lk];
#pragma unroll
    for (int f = 0; f < 4; ++f) bfr[f] = *(const short8*)&Bs[(wc * 64 + f * 16 + lr) * 32 + lk];
#pragma unroll
    for (int fm = 0; fm < 4; ++fm)
#pragma unroll
      for (int fn = 0; fn < 4; ++fn)
        acc[fm][fn] = __builtin_amdgcn_mfma_f32_16x16x32_bf16(af[fm], bfr[fn], acc[fm][fn], 0, 0, 0);
    __syncthreads();
  }
  long cz = (long)z * sC;
  long rz = (long)z * sR;
  int li = (l >> 4) * 4, lj = l & 15;
#pragma unroll
  for (int fm = 0; fm < 4; ++fm)
#pragma unroll
    for (int fn = 0; fn < 4; ++fn) {
      long ib = i0 + wr * 64 + fm * 16 + li;
      long j  = j0 + wc * 64 + fn * 16 + lj;
#pragma unroll
      for (int r = 0; r < 4; ++r) {
        long i = ib + r;
        float v = acc[fm][fn][r] * alpha;
        if (BIASCOL) v += bias[j];
        if (BIASROW) v += bias[i];
        if (RES)     v += res[rz + i * ldc + j];
        if (RELU)    v = fmaxf(v, 0.f);
        if (OUTBF) ((unsigned short*)Cout)[cz + i * ldc + j] = f2bf(v);
        else       ((float*)Cout)[cz + i * ldc + j] = v;
      }
    }
  if (STATS) {
    // per-column (j) max & sum-exp over this warp's 64 rows -> part[z*16+chunk][n]
    int chunk = blockIdx.y * 2 + wr;
#pragma unroll
    for (int fn = 0; fn < 4; ++fn) {
      float mx = -1e30f;
#pragma unroll
      for (int fm = 0; fm < 4; ++fm)
#pragma unroll
        for (int r = 0; r < 4; ++r) mx = fmaxf(mx, acc[fm][fn][r]);
      mx = fmaxf(mx, __shfl_xor(mx, 16));
      mx = fmaxf(mx, __shfl_xor(mx, 32));
      float sm = 0.f;
#pragma unroll
      for (int fm = 0; fm < 4; ++fm)
#pragma unroll
        for (int r = 0; r < 4; ++r) sm += __expf(acc[fm][fn][r] - mx);
      sm += __shfl_xor(sm, 16);
      sm += __shfl_xor(sm, 32);
      if (l < 16) {
        long n = j0 + wc * 64 + fn * 16 + l;
        part[((long)z * 16 + chunk) * NN + n] = make_float2(mx, sm);
      }
    }
  }
}

// ---------- PV GEMM, K-split x4, fused stat-combine + exp ----------
// xrp[s][q][m][c] = (1/16) sum_{n in s-chunk} p(E[q][m][n]) * xv[q%4][c][n]
__global__ __launch_bounds__(256) void pv_gemm(
    const unsigned short* __restrict__ E, const unsigned short* __restrict__ XV,
    const float2* __restrict__ part, float* __restrict__ xrp) {
  __shared__ unsigned short As[128 * 32];
  __shared__ unsigned short Bs[128 * 32];
  __shared__ float Ms[256];
  __shared__ float Ds[256];
  int z = blockIdx.z;
  int q = z >> 2, s = z & 3;
  const unsigned short* A = E + (long)q * NN * NN + s * 256;
  const unsigned short* B = XV + (long)(q & 3) * CN + s * 256;
  int t = threadIdx.x;
  {
    int n = s * 256 + t;
    float mx = -1e30f;
#pragma unroll
    for (int c = 0; c < 16; ++c) mx = fmaxf(mx, part[((long)q * 16 + c) * NN + n].x);
    float sm = 0.f;
#pragma unroll
    for (int c = 0; c < 16; ++c) {
      float2 p = part[((long)q * 16 + c) * NN + n];
      sm += p.y * __expf(p.x - mx);
    }
    Ms[t] = mx;
    Ds[t] = 1.f / sm;
  }
  int w = t >> 6, l = t & 63;
  int wr = w >> 1, wc = w & 1;
  long i0 = blockIdx.y * 128, j0 = blockIdx.x * 128;
  f32x4 acc[4][4];
#pragma unroll
  for (int a = 0; a < 4; ++a)
#pragma unroll
    for (int b = 0; b < 4; ++b) acc[a][b] = (f32x4){0.f, 0.f, 0.f, 0.f};
  int lr = l & 15, lk = (l >> 4) * 8;
  int ar = t >> 1, ah = (t & 1) * 16;
  __syncthreads();
  for (int k0 = 0; k0 < 256; k0 += 32) {
#pragma unroll
    for (int it = 0; it < 2; ++it) {
      int chunk = t + it * 256;
      int row = chunk >> 2, kq = chunk & 3;
      gload_lds16(B + (j0 + row) * 1024L + k0 + kq * 8, &Bs[chunk * 8]);
    }
    u16x8 e0 = *(const u16x8*)&A[(i0 + ar) * 1024L + k0 + ah];
    u16x8 e1 = *(const u16x8*)&A[(i0 + ar) * 1024L + k0 + ah + 8];
    u16x8 p0, p1;
#pragma unroll
    for (int j = 0; j < 8; ++j) {
      int n = k0 + ah + j;
      p0[j] = f2bf(__expf(bf2f(e0[j]) - Ms[n]) * Ds[n]);
    }
#pragma unroll
    for (int j = 0; j < 8; ++j) {
      int n = k0 + ah + 8 + j;
      p1[j] = f2bf(__expf(bf2f(e1[j]) - Ms[n]) * Ds[n]);
    }
    *(u16x8*)&As[ar * 32 + ah]     = p0;
    *(u16x8*)&As[ar * 32 + ah + 8] = p1;
    __syncthreads();
    short8 af[4], bfr[4];
#pragma unroll
    for (int f = 0; f < 4; ++f) af[f]  = *(const short8*)&As[(wr * 64 + f * 16 + lr) * 32 + lk];
#pragma unroll
    for (int f = 0; f < 4; ++f) bfr[f] = *(const short8*)&Bs[(wc * 64 + f * 16 + lr) * 32 + lk];
#pragma unroll
    for (int fm = 0; fm < 4; ++fm)
#pragma unroll
      for (int fn = 0; fn < 4; ++fn)
        acc[fm][fn] = __builtin_amdgcn_mfma_f32_16x16x32_bf16(af[fm], bfr[fn], acc[fm][fn], 0, 0, 0);
    __syncthreads();
  }
  long cz = (long)(s * 12 + q) << 18;   // * NN*CC
  int li = (l >> 4) * 4, lj = l & 15;
#pragma unroll
  for (int fm = 0; fm < 4; ++fm)
#pragma unroll
    for (int fn = 0; fn < 4; ++fn) {
      long ib = i0 + wr * 64 + fm * 16 + li;
      long j  = j0 + wc * 64 + fn * 16 + lj;
#pragma unroll
      for (int r = 0; r < 4; ++r)
        xrp[cz + (ib + r) * 256 + j] = acc[fm][fn][r] * (1.f / 16.f);
    }
}

// ---------- mix (reshape-mean over 12 partials) + residual + LN1 ----------
__global__ __launch_bounds__(256) void mix_ln1(
    const unsigned short* __restrict__ xT, const float* __restrict__ xrp,
    const float* __restrict__ g, const float* __restrict__ bb,
    float* __restrict__ h, unsigned short* __restrict__ h_bf) {
  __shared__ float r1[4], r2[4];
  int bn = blockIdx.x;
  int i = bn >> 10, n = bn & 1023;
  int c = threadIdx.x;
  long no = (long)n * CC + c;
  float a = 0.f;
#pragma unroll
  for (int j = 0; j < 3; ++j)
#pragma unroll
    for (int s = 0; s < 4; ++s)
      a += xrp[((long)(s * 12 + 3 * i + j) << 18) + no];
  float v = bf2f(xT[(long)i * CN + no]) + a * (1.f / 3.f);
  float sS = v, s2 = v * v;
#pragma unroll
  for (int m = 32; m; m >>= 1) { sS += __shfl_xor(sS, m); s2 += __shfl_xor(s2, m); }
  if ((c & 63) == 0) { r1[c >> 6] = sS; r2[c >> 6] = s2; }
  __syncthreads();
  float mu = (r1[0] + r1[1] + r1[2] + r1[3]) * (1.f / 256.f);
  float var = (r2[0] + r2[1] + r2[2] + r2[3]) * (1.f / 256.f) - mu * mu;
  float o = (v - mu) * rsqrtf(var + 1e-6f) * g[c] + bb[c];
  h[(long)bn * CC + c] = o;
  h_bf[(long)bn * CC + c] = f2bf(o);
}

// ---------- combine MLP2 partials + bias + residual + LN2 + relu + transpose ----------
__global__ __launch_bounds__(256) void ln2t(
    const float* __restrict__ pm, const float* __restrict__ h,
    const float* __restrict__ b2, const float* __restrict__ g,
    const float* __restrict__ bb, float* __restrict__ out) {
  __shared__ float tile[16][261];
  __shared__ float smu[16], srs[16];
  int i = blockIdx.y, n0 = blockIdx.x * 16;
  int t = threadIdx.x;
  float bc = b2[t];
#pragma unroll
  for (int r = 0; r < 16; ++r) {
    long row = (long)i * NN + n0 + r;
    float v = bc + h[row * CC + t];
#pragma unroll
    for (int s = 0; s < 4; ++s) v += pm[((long)s << 20) + row * CC + t];
    tile[r][t] = v;
  }
  __syncthreads();
  int w = t >> 6, l = t & 63;
#pragma unroll
  for (int rr = 0; rr < 4; ++rr) {
    int r = w * 4 + rr;
    float s = 0.f, s2 = 0.f;
#pragma unroll
    for (int k = 0; k < 4; ++k) { float v = tile[r][l + 64 * k]; s += v; s2 += v * v; }
#pragma unroll
    for (int m = 32; m; m >>= 1) { s += __shfl_xor(s, m); s2 += __shfl_xor(s2, m); }
    if (l == 0) {
      float mu = s * (1.f / 256.f);
      float var = s2 * (1.f / 256.f) - mu * mu;
      smu[r] = mu; srs[r] = rsqrtf(var + 1e-6f);
    }
  }
  __syncthreads();
#pragma unroll
  for (int k = 0; k < 16; ++k) {
    int nn = t & 15, c = (t >> 4) + 16 * k;
    float v = (tile[nn][c] - smu[nn]) * srs[nn] * g[c] + bb[c];
    out[((long)i * CC + c) * NN + n0 + nn] = fmaxf(v, 0.f);
  }
}

extern "C" void kernel_launch(void* const* d_in, const int* in_sizes, int n_in,
                              void* d_out, int out_size, void* d_ws, size_t ws_size,
                              hipStream_t stream) {
  const float* x   = (const float*)d_in[0];
  const float* Wq  = (const float*)d_in[1];
  const float* Wk  = (const float*)d_in[2];
  const float* Wv  = (const float*)d_in[3];
  const float* bv  = (const float*)d_in[4];
  const float* g1  = (const float*)d_in[5];
  const float* b1v = (const float*)d_in[6];
  const float* W1  = (const float*)d_in[7];
  const float* b1m = (const float*)d_in[8];
  const float* W2  = (const float*)d_in[9];
  const float* b2m = (const float*)d_in[10];
  const float* g2  = (const float*)d_in[11];
  const float* b2v = (const float*)d_in[12];
  float* out = (float*)d_out;

  char* base = (char*)d_ws;
  // [0,24MB): E_bf; reused after PV: h [0,4), h_bf [4,6), hid_bf [6,14)
  unsigned short* E_bf   = (unsigned short*)base;
  float*          h      = (float*)base;
  unsigned short* h_bf   = (unsigned short*)(base + (4u << 20));
  unsigned short* hid_bf = (unsigned short*)(base + (6u << 20));
  size_t off = 24u << 20;
  float* xrp             = (float*)(base + off);          off += 50331648;  // 48MB
  float* p_mlp           = (float*)(base + off);          off += 16777216;  // 16MB
  unsigned short* wv_bf  = (unsigned short*)(base + off); off += 131072;
  unsigned short* w1_bf  = (unsigned short*)(base + off); off += 524288;
  unsigned short* w2_bf  = (unsigned short*)(base + off); off += 524288;
  unsigned short* xt_bf  = (unsigned short*)(base + off); off += 2097152;
  unsigned short* xqt_bf = (unsigned short*)(base + off); off += 6291456;
  unsigned short* xkt_bf = (unsigned short*)(base + off); off += 2097152;
  unsigned short* xv_bf  = (unsigned short*)(base + off); off += 2097152;
  float2* part           = (float2*)(base + off);         off += 1572864;

  // 1. prep: weights->bf16 (576) + x-transpose (256) + projections (1024)
  prep_kernel<<<1856, 256, 0, stream>>>(x, Wq, Wk, (const float4*)Wv,
      (const float4*)W1, (const float4*)W2, wv_bf, w1_bf, w2_bf,
      xt_bf, xqt_bf, xkt_bf);
  // 2. xv_bf[b][o][n] = Wv x[b] + bv
  mgemm<1,0,0,0,1,0><<<dim3(8, 2, 4), 256, 0, stream>>>(
      wv_bf, xt_bf, xv_bf, bv, nullptr, nullptr,
      256, 256, 1024, 256, 0L, 1, (long)CN, 4, (long)CN, 0L, 1.f);
  // 3. E'[q][m][n] = sum_c xk[c][m] xq[c][n]  (bf16) + fused per-column stats
  mgemm<0,0,0,0,1,1><<<dim3(8, 8, 12), 256, 0, stream>>>(
      xkt_bf, xqt_bf, E_bf, nullptr, nullptr, part,
      256, 256, 1024, 256, (long)CN, 4, (long)CN, 12, (long)NN * NN, 0L, 1.f);
  // 4. PV (K-split x4) with fused stat-combine + exp -> xrp f32
  pv_gemm<<<dim3(2, 8, 48), 256, 0, stream>>>(E_bf, xv_bf, part, xrp);
  // 5. mix + LN1 -> h (f32) + h_bf
  mix_ln1<<<4096, 256, 0, stream>>>(xt_bf, xrp, g1, b1v, h, h_bf);
  // 6. hid = relu(h @ W1^T + b1) -> bf16
  mgemm<0,1,1,0,1,0><<<dim3(8, 32, 1), 256, 0, stream>>>(
      h_bf, w1_bf, hid_bf, b1m, nullptr, nullptr,
      256, 256, 1024, 256, 0L, 1, 0L, 1, 0L, 0L, 1.f);
  // 7. MLP2 partials (K-split x4): p_mlp[s] = hid[:,s*256:] @ W2[:,s*256:]^T
  mgemm<0,0,0,0,0,0><<<dim3(2, 32, 4), 256, 0, stream>>>(
      hid_bf, w2_bf, p_mlp, nullptr, nullptr, nullptr,
      1024, 1024, 256, 256, 256L, 4, 256L, 4, 1048576L, 0L, 1.f);
  // 8. combine + bias + residual + LN2 + relu + transpose -> out[0..3]
  ln2t<<<dim3(64, 4), 256, 0, stream>>>(p_mlp, h, b2m, g2, b2v, out);
  // 9. passthrough batches 4..15
  hipMemcpyAsync(out + 4L * CN, x + 4L * CN, 12L * CN * sizeof(float),
                 hipMemcpyDeviceToDevice, stream);
}